// Round 1
// baseline (11.423 us; speedup 1.0000x reference)
//
#include <hip/hip_runtime.h>
#include <math.h>

#define NUM_BASIC 2
#define NUM_MIXED 4
#define NUM_FRAME 8
#define NUM_NODES 7
#define CLIP_LEN  8
#define GROUP     7
#define NN        57              // N = 1 + NUM_NODES*NUM_FRAME
#define TT        15              // T = 2*NUM_FRAME - 1
#define MIXED_COLS (TT * NUM_NODES)   // 105

__global__ __launch_bounds__(256) void pattern_mixer_kernel(
    const float* __restrict__ mat,          // (2,7,7)
    const float* __restrict__ te,           // (4,2,15)
    const float* __restrict__ mixer_w,      // (4,2)
    const float* __restrict__ mixer_b,      // (4,)
    const float* __restrict__ mmp,          // (4,57,57)
    float* __restrict__ out)                // (4,57,57)
{
    const int i   = blockIdx.x;     // mixed index 0..3
    const int tid = threadIdx.x;

    __shared__ float mm[NN * NN];               // 3249 floats
    __shared__ float mixed[NUM_NODES * MIXED_COLS]; // 7*105 = 735
    __shared__ float sig[NUM_BASIC * TT];       // 30
    __shared__ float d[NN];

    // Phase 1: load mixed_mat_param[i] into LDS (never mutate the input)
    for (int k = tid; k < NN * NN; k += blockDim.x)
        mm[k] = mmp[i * NN * NN + k];

    // sigmoid(temporal_expansion[i])
    if (tid < NUM_BASIC * TT) {
        float x = te[i * NUM_BASIC * TT + tid];
        sig[tid] = 1.0f / (1.0f + expf(-x));
    }
    __syncthreads();

    // Phase 2: mixed[n][t*7+m] = relu( sum_h w[h]*sig[h][t]*mat[h][n][m] + b )
    const float w0 = mixer_w[i * NUM_BASIC + 0];
    const float w1 = mixer_w[i * NUM_BASIC + 1];
    const float b  = mixer_b[i];
    for (int k = tid; k < NUM_NODES * MIXED_COLS; k += blockDim.x) {
        int n = k / MIXED_COLS;
        int c = k % MIXED_COLS;
        int t = c / NUM_NODES;
        int m = c % NUM_NODES;
        float v = w0 * sig[t] * mat[0 * 49 + n * 7 + m]
                + w1 * sig[TT + t] * mat[1 * 49 + n * 7 + m]
                + b;
        mixed[k] = fmaxf(v, 0.0f);
    }
    __syncthreads();

    // Phase 3: clip accumulation.
    // For iclip in 0..7: mm[1+7*iclip+n][1+c] += mixed[n][7*(7-iclip)+c], c in 0..55.
    // Each (iclip, n) hits a distinct row -> every k targets a unique element, no races.
    for (int k = tid; k < CLIP_LEN * NUM_NODES * 56; k += blockDim.x) {
        int iclip = k / (NUM_NODES * 56);
        int rem   = k % (NUM_NODES * 56);
        int n     = rem / 56;
        int c     = rem % 56;
        mm[(1 + 7 * iclip + n) * NN + 1 + c] += mixed[n * MIXED_COLS + 7 * (7 - iclip) + c];
    }
    __syncthreads();

    // Phase 4: zero mask on rows 7,14,...,56
    for (int k = tid; k < CLIP_LEN * NN; k += blockDim.x) {
        int blk = k / NN;
        int col = k % NN;
        int row = 7 * (blk + 1);
        bool own = (col >= 1 + 7 * blk) && (col <= 7 * (blk + 1));
        if (col >= 1 && (col % 7) != 0 && !own)
            mm[row * NN + col] = 0.0f;
    }
    __syncthreads();

    // Phase 5: row sums -> d[r] = rsqrt(max(sum, 1))
    if (tid < NN) {
        float s = 0.0f;
        const float* rowp = &mm[tid * NN];
        #pragma unroll
        for (int c = 0; c < NN; ++c) s += rowp[c];
        d[tid] = rsqrtf(fmaxf(s, 1.0f));
    }
    __syncthreads();

    // Phase 6: out = d[r] * mm * d[c]
    for (int k = tid; k < NN * NN; k += blockDim.x) {
        int r = k / NN;
        int c = k % NN;
        out[i * NN * NN + k] = d[r] * mm[k] * d[c];
    }
}

extern "C" void kernel_launch(void* const* d_in, const int* in_sizes, int n_in,
                              void* d_out, int out_size, void* d_ws, size_t ws_size,
                              hipStream_t stream) {
    const float* mat     = (const float*)d_in[0];
    const float* te      = (const float*)d_in[1];
    const float* mixer_w = (const float*)d_in[2];
    const float* mixer_b = (const float*)d_in[3];
    const float* mmp     = (const float*)d_in[4];
    float* out           = (float*)d_out;

    pattern_mixer_kernel<<<NUM_MIXED, 256, 0, stream>>>(mat, te, mixer_w, mixer_b, mmp, out);
}

// Round 2
// 10.599 us; speedup vs baseline: 1.0777x; 1.0777x over previous
//
#include <hip/hip_runtime.h>
#include <math.h>

#define NUM_MIXED 4
#define NN        57              // N = 1 + 7*8
#define TT        15              // T = 2*8 - 1

__global__ __launch_bounds__(256) void pattern_mixer_kernel(
    const float* __restrict__ mat,          // (2,7,7)
    const float* __restrict__ te,           // (4,2,15)
    const float* __restrict__ mixer_w,      // (4,2)
    const float* __restrict__ mixer_b,      // (4,)
    const float* __restrict__ mmp,          // (4,57,57)
    float* __restrict__ out)                // (4,57,57)
{
    const int i   = blockIdx.x;     // mixed index 0..3
    const int tid = threadIdx.x;

    __shared__ float s_mat[2 * 49];          // 98
    __shared__ float s_sig[2 * TT];          // 30
    __shared__ float s_mixed[7 * 105];       // 735
    __shared__ float s_mm[NN * NN];          // 3249
    __shared__ float s_d[NN];

    // Phase A: sigmoid(te[i]) and stage mat into LDS
    if (tid < 30) {
        float x = te[i * 30 + tid];
        s_sig[tid] = 1.0f / (1.0f + expf(-x));
    } else if (tid >= 32 && tid < 32 + 98) {
        s_mat[tid - 32] = mat[tid - 32];
    }
    __syncthreads();

    // Phase B: mixed[n][t*7+m] = relu(w0*sig0[t]*mat0[n][m] + w1*sig1[t]*mat1[n][m] + b)
    const float w0 = mixer_w[i * 2 + 0];
    const float w1 = mixer_w[i * 2 + 1];
    const float b  = mixer_b[i];
    for (int k = tid; k < 735; k += 256) {
        int n = k / 105;
        int c = k % 105;
        int t = c / 7;
        int m = c % 7;
        float v = fmaf(w0 * s_sig[t], s_mat[n * 7 + m],
                  fmaf(w1 * s_sig[TT + t], s_mat[49 + n * 7 + m], b));
        s_mixed[k] = fmaxf(v, 0.0f);
    }
    __syncthreads();

    // Phase C: fused mm construction + row sums. 4 lanes per row (228 active).
    // mm[r][c] = mmp[i][r][c]
    //          + (r>=1 && c>=1 ? mixed[(r-1)%7][7*(7-(r-1)/7) + (c-1)] : 0)
    //   then zero-masked on rows r = 7,14,...,56.
    if (tid < 228) {
        const int r = tid >> 2;
        const int q = tid & 3;
        const int iclip = (r - 1) / 7;        // only used when r>=1
        const int n     = (r - 1) % 7;
        const bool maskrow = (r > 0) && (r % 7 == 0);
        const int blk = r / 7 - 1;            // only used when maskrow
        const float* __restrict__ basep  = mmp + i * NN * NN + r * NN;
        const float* __restrict__ mixp   = s_mixed + n * 105 + 7 * (7 - iclip) - 1;

        float s = 0.0f;
        for (int c = q; c < NN; c += 4) {
            float v = basep[c];
            if (r >= 1 && c >= 1)
                v += mixp[c];
            if (maskrow) {
                bool own = (c >= 1 + 7 * blk) && (c <= 7 * blk + 7);
                if (c >= 1 && (c % 7) != 0 && !own)
                    v = 0.0f;
            }
            s_mm[r * NN + c] = v;
            s += v;
        }
        s += __shfl_xor(s, 1);
        s += __shfl_xor(s, 2);
        if (q == 0)
            s_d[r] = rsqrtf(fmaxf(s, 1.0f));
    }
    __syncthreads();

    // Phase D: out = d[r] * mm * d[c], coalesced
    float* __restrict__ outp = out + i * NN * NN;
    for (int k = tid; k < NN * NN; k += 256) {
        int r = k / NN;
        int c = k % NN;
        outp[k] = s_d[r] * s_mm[k] * s_d[c];
    }
}

extern "C" void kernel_launch(void* const* d_in, const int* in_sizes, int n_in,
                              void* d_out, int out_size, void* d_ws, size_t ws_size,
                              hipStream_t stream) {
    const float* mat     = (const float*)d_in[0];
    const float* te      = (const float*)d_in[1];
    const float* mixer_w = (const float*)d_in[2];
    const float* mixer_b = (const float*)d_in[3];
    const float* mmp     = (const float*)d_in[4];
    float* out           = (float*)d_out;

    pattern_mixer_kernel<<<NUM_MIXED, 256, 0, stream>>>(mat, te, mixer_w, mixer_b, mmp, out);
}

// Round 3
// 9.711 us; speedup vs baseline: 1.1762x; 1.0914x over previous
//
#include <hip/hip_runtime.h>
#include <math.h>

#define NUM_MIXED 4
#define NN        57              // N = 1 + 7*8

// 8 lanes per row, 57 rows -> 456 active threads, one block per mixed-index i.
// Lane (r, q) owns columns c = 7q+1 .. 7q+7 (q=0 also owns c=0).
// Static per-lane facts:
//   t      = (7 - iclip) + q      (single temporal index -> 2 sigmoids/thread)
//   m      = j                    (static index into mat row n)
//   own    = (q == blk)           (zero-mask block test)
//   c % 7 == 0  <=>  j == 6       (zero-mask column test)
__global__ __launch_bounds__(512) void pattern_mixer_kernel(
    const float* __restrict__ mat,          // (2,7,7)
    const float* __restrict__ te,           // (4,2,15)
    const float* __restrict__ mixer_w,      // (4,2)
    const float* __restrict__ mixer_b,      // (4,)
    const float* __restrict__ mmp,          // (4,57,57)
    float* __restrict__ out)                // (4,57,57)
{
    const int i   = blockIdx.x;
    const int tid = threadIdx.x;
    const bool active = tid < 456;
    const int r = tid >> 3;      // row 0..56
    const int q = tid & 7;       // column group 0..7

    __shared__ float s_d[NN];

    float v[7];
    float v0 = 0.0f;

    if (active) {
        // Issue the global mmp loads first so their latency hides under the ALU work.
        const float* __restrict__ bp = mmp + i * NN * NN + r * NN;
        float base[7];
        #pragma unroll
        for (int j = 0; j < 7; ++j) base[j] = bp[7 * q + 1 + j];
        if (q == 0) v0 = bp[0];

        const bool rge1  = (r >= 1);
        const int  n     = rge1 ? (r - 1) % 7 : 0;
        const int  iclip = rge1 ? (r - 1) / 7 : 0;
        const int  t     = (7 - iclip) + q;          // in [0,14]

        const float w0 = mixer_w[i * 2 + 0];
        const float w1 = mixer_w[i * 2 + 1];
        const float b  = mixer_b[i];
        const float x0 = te[i * 30 + t];
        const float x1 = te[i * 30 + 15 + t];
        const float a0 = w0 / (1.0f + expf(-x0));    // w0 * sigmoid(x0)
        const float a1 = w1 / (1.0f + expf(-x1));

        const bool maskrow = rge1 && ((r % 7) == 0);
        const int  blk     = r / 7 - 1;
        const bool zerome  = maskrow && (q != blk);

        float s = v0;   // c=0 contribution (q==0 only)
        #pragma unroll
        for (int j = 0; j < 7; ++j) {
            float val = base[j];
            if (rge1) {
                float mx = fmaf(a0, mat[n * 7 + j],
                           fmaf(a1, mat[49 + n * 7 + j], b));
                val += fmaxf(mx, 0.0f);
            }
            if (zerome && j != 6) val = 0.0f;        // c%7!=0 && !own -> zero
            v[j] = val;
            s += val;
        }
        // row-sum across the 8-lane group (group is wave-aligned: 456 = 57*8)
        s += __shfl_xor(s, 1);
        s += __shfl_xor(s, 2);
        s += __shfl_xor(s, 4);
        if (q == 0) s_d[r] = rsqrtf(fmaxf(s, 1.0f));
    }

    __syncthreads();   // single barrier: publish d[]

    if (active) {
        const float dr = s_d[r];
        float* __restrict__ op = out + i * NN * NN + r * NN;
        #pragma unroll
        for (int j = 0; j < 7; ++j) {
            int c = 7 * q + 1 + j;
            op[c] = dr * v[j] * s_d[c];
        }
        if (q == 0) op[0] = dr * v0 * s_d[0];
    }
}

extern "C" void kernel_launch(void* const* d_in, const int* in_sizes, int n_in,
                              void* d_out, int out_size, void* d_ws, size_t ws_size,
                              hipStream_t stream) {
    const float* mat     = (const float*)d_in[0];
    const float* te      = (const float*)d_in[1];
    const float* mixer_w = (const float*)d_in[2];
    const float* mixer_b = (const float*)d_in[3];
    const float* mmp     = (const float*)d_in[4];
    float* out           = (float*)d_out;

    pattern_mixer_kernel<<<NUM_MIXED, 512, 0, stream>>>(mat, te, mixer_w, mixer_b, mmp, out);
}

// Round 5
// 9.693 us; speedup vs baseline: 1.1785x; 1.0019x over previous
//
#include <hip/hip_runtime.h>
#include <math.h>

#define NUM_MIXED 4
#define NN        57              // N = 1 + 7*8

// 8 lanes per row, 57 rows -> 456 active threads, one block per mixed-index i.
// Lane (r, q) owns columns c = 7q+1 .. 7q+7 (q=0 also owns c=0).
__global__ __launch_bounds__(512) void pattern_mixer_kernel(
    const float* __restrict__ mat,          // (2,7,7)
    const float* __restrict__ te,           // (4,2,15)
    const float* __restrict__ mixer_w,      // (4,2)
    const float* __restrict__ mixer_b,      // (4,)
    const float* __restrict__ mmp,          // (4,57,57)
    float* __restrict__ out)                // (4,57,57)
{
    const int i   = blockIdx.x;
    const int tid = threadIdx.x;
    const bool active = tid < 456;
    const int r = tid >> 3;      // row 0..56
    const int q = tid & 7;       // column group 0..7

    __shared__ float s_d[NN];

    float v[7];
    float v0 = 0.0f;

    if (active) {
        // Issue the global mmp loads first so their latency hides under the ALU work.
        const float* __restrict__ bp = mmp + i * NN * NN + r * NN;
        float base[7];
        #pragma unroll
        for (int j = 0; j < 7; ++j) base[j] = bp[7 * q + 1 + j];
        if (q == 0) v0 = bp[0];

        const bool rge1  = (r >= 1);
        const int  n     = rge1 ? (r - 1) % 7 : 0;
        const int  iclip = rge1 ? (r - 1) / 7 : 0;
        const int  t     = (7 - iclip) + q;          // in [0,14]

        const float w0 = mixer_w[i * 2 + 0];
        const float w1 = mixer_w[i * 2 + 1];
        const float b  = mixer_b[i];
        const float x0 = te[i * 30 + t];
        const float x1 = te[i * 30 + 15 + t];
        // w * sigmoid(x) = w * rcp(1 + 2^(-x*log2e)), native v_exp_f32 + v_rcp_f32
        const float LOG2E = 1.4426950408889634f;
        const float e0 = __builtin_amdgcn_exp2f(-x0 * LOG2E);
        const float e1 = __builtin_amdgcn_exp2f(-x1 * LOG2E);
        const float a0 = w0 * __builtin_amdgcn_rcpf(1.0f + e0);
        const float a1 = w1 * __builtin_amdgcn_rcpf(1.0f + e1);

        const bool maskrow = rge1 && ((r % 7) == 0);
        const int  blk     = r / 7 - 1;
        const bool zerome  = maskrow && (q != blk);

        float s = v0;   // c=0 contribution (q==0 only)
        #pragma unroll
        for (int j = 0; j < 7; ++j) {
            float val = base[j];
            if (rge1) {
                float mx = fmaf(a0, mat[n * 7 + j],
                           fmaf(a1, mat[49 + n * 7 + j], b));
                val += fmaxf(mx, 0.0f);
            }
            if (zerome && j != 6) val = 0.0f;        // c%7!=0 && !own -> zero
            v[j] = val;
            s += val;
        }
        // row-sum across the 8-lane group (group is wave-aligned: 456 = 57*8)
        s += __shfl_xor(s, 1);
        s += __shfl_xor(s, 2);
        s += __shfl_xor(s, 4);
        if (q == 0) s_d[r] = rsqrtf(fmaxf(s, 1.0f));
    }

    __syncthreads();   // single barrier: publish d[]

    if (active) {
        const float dr = s_d[r];
        float* __restrict__ op = out + i * NN * NN + r * NN;
        #pragma unroll
        for (int j = 0; j < 7; ++j) {
            int c = 7 * q + 1 + j;
            op[c] = dr * v[j] * s_d[c];
        }
        if (q == 0) op[0] = dr * v0 * s_d[0];
    }
}

extern "C" void kernel_launch(void* const* d_in, const int* in_sizes, int n_in,
                              void* d_out, int out_size, void* d_ws, size_t ws_size,
                              hipStream_t stream) {
    const float* mat     = (const float*)d_in[0];
    const float* te      = (const float*)d_in[1];
    const float* mixer_w = (const float*)d_in[2];
    const float* mixer_b = (const float*)d_in[3];
    const float* mmp     = (const float*)d_in[4];
    float* out           = (float*)d_out;

    pattern_mixer_kernel<<<NUM_MIXED, 512, 0, stream>>>(mat, te, mixer_w, mixer_b, mmp, out);
}